// Round 1
// baseline (485.193 us; speedup 1.0000x reference)
//
#include <hip/hip_runtime.h>
#include <stdint.h>

typedef short bf16x8 __attribute__((ext_vector_type(8)));
typedef float f32x4  __attribute__((ext_vector_type(4)));

// ---------- helpers ----------
__device__ __forceinline__ uint16_t f2bf(float f) {
  uint32_t u = __builtin_bit_cast(uint32_t, f);
  u += 0x7fffu + ((u >> 16) & 1u);          // RNE
  return (uint16_t)(u >> 16);
}
__device__ __forceinline__ float bf2f(uint16_t h) {
  uint32_t u = ((uint32_t)h) << 16;
  return __builtin_bit_cast(float, u);
}

// Convert both weight matrices (512x768 fp32 each) to bf16 in workspace.
__global__ void convw_kernel(const float* __restrict__ wf,
                             const float* __restrict__ wn,
                             uint16_t* __restrict__ o) {
  int i4 = (blockIdx.x * 256 + threadIdx.x) * 4;   // 786432 total elems
  float4 v;
  if (i4 < 393216) v = *(const float4*)(wf + i4);
  else             v = *(const float4*)(wn + (i4 - 393216));
  ushort4 b;
  b.x = f2bf(v.x); b.y = f2bf(v.y); b.z = f2bf(v.z); b.w = f2bf(v.w);
  *(ushort4*)(o + i4) = b;
}

// ---------- staging ----------
// A-tile [64 rows][32 k] bf16, converted from fp32 global (hx for k<512, x after).
__device__ __forceinline__ void stage_a(uint16_t* sAbuf,
                                        const float* __restrict__ x,
                                        const float* __restrict__ hx,
                                        int blockRow, int k0, int tid) {
  const int r  = tid >> 3;            // 0..63
  const int c4 = (tid & 7) << 2;      // 0,4,...,28
  const float* src; int ld, col;
  if (k0 < 512) { src = hx; ld = 512; col = k0 + c4; }
  else          { src = x;  ld = 256; col = k0 - 512 + c4; }
  float4 v = *(const float4*)(src + (size_t)(blockRow + r) * ld + col);
  ushort4 b;
  b.x = f2bf(v.x); b.y = f2bf(v.y); b.z = f2bf(v.z); b.w = f2bf(v.w);
  *(ushort4*)(sAbuf + r * 32 + c4) = b;
}

// B-tile [512 n][32 k] bf16 from pre-converted weights via global_load_lds (16B).
__device__ __forceinline__ void stage_b(uint16_t* sBbuf, const uint16_t* __restrict__ w,
                                        int k0, int wave, int lane) {
#pragma unroll
  for (int i = 0; i < 4; ++i) {
    int grp = i * 8 + wave;                       // 0..31 (wave-uniform)
    int h   = grp * 16 + (lane >> 2);             // output col
    int ke  = (lane & 3) * 8;                     // k element offset
    const uint16_t* g = w + (size_t)h * 768 + k0 + ke;   // per-lane src
    uint16_t* l = sBbuf + grp * 512;              // wave-uniform dst (+lane*16 by HW)
    __builtin_amdgcn_global_load_lds(
        (const __attribute__((address_space(1))) uint32_t*)g,
        (__attribute__((address_space(3))) uint32_t*)l, 16, 0, 0);
  }
}

// ---------- fragment loads + MFMA ----------
__device__ __forceinline__ void load_a_sa(const uint16_t* sAbuf, bf16x8 a[2],
                                          int rl, int kg, int wm) {
#pragma unroll
  for (int mf = 0; mf < 2; ++mf)
    a[mf] = *(const bf16x8*)(sAbuf + (wm * 32 + mf * 16 + rl) * 32 + kg * 8);
}
__device__ __forceinline__ void load_a_fx(const uint16_t* sFX, bf16x8 a[2],
                                          int k0, int rl, int kg, int wm) {
#pragma unroll
  for (int mf = 0; mf < 2; ++mf) {
    int row = wm * 32 + mf * 16 + rl;
    int idx = (row * 512 + k0 + kg * 8) ^ ((row & 7) << 3);  // XOR swizzle
    a[mf] = *(const bf16x8*)(sFX + idx);
  }
}
__device__ __forceinline__ void mfma_core(const bf16x8 a[2], const uint16_t* sBbuf,
                                          f32x4 acc[2][8], int rl, int kg, int wn4) {
  bf16x8 b[8];
#pragma unroll
  for (int nf = 0; nf < 8; ++nf)
    b[nf] = *(const bf16x8*)(sBbuf + (wn4 * 128 + nf * 16 + rl) * 32 + kg * 8);
#pragma unroll
  for (int mf = 0; mf < 2; ++mf)
#pragma unroll
    for (int nf = 0; nf < 8; ++nf)
      acc[mf][nf] = __builtin_amdgcn_mfma_f32_16x16x32_bf16(a[mf], b[nf], acc[mf][nf], 0, 0, 0);
}

// ---------- fused cell kernel ----------
// grid 1024 x 512 threads; per block: 64 rows x 512 cols, both GEMMs fused.
__global__ __launch_bounds__(512) void fsumgu_kernel(
    const float* __restrict__ x,  const float* __restrict__ hx,
    const float* __restrict__ bf_, const float* __restrict__ bn_,
    const uint16_t* __restrict__ wf, const uint16_t* __restrict__ wn,
    float* __restrict__ out)
{
  extern __shared__ float4 smem4[];
  char* smem = (char*)smem4;
  uint16_t* sA  = (uint16_t*)smem;                    // 2 x [64][32]  = 8 KB
  uint16_t* sB  = (uint16_t*)(smem + 8192);           // 2 x [512][32] = 64 KB
  uint16_t* sFX = (uint16_t*)(smem + 8192 + 65536);   // [64][512]     = 64 KB (swizzled)

  const int tid  = threadIdx.x;
  const int lane = tid & 63;
  const int wave = tid >> 6;
  const int wm   = wave >> 2;      // 0..1  (32-row strip)
  const int wn4  = wave & 3;       // 0..3  (128-col strip)
  const int rl   = lane & 15;
  const int kg   = lane >> 4;
  const int blockRow = blockIdx.x * 64;

  f32x4 acc1[2][8], acc2[2][8];
#pragma unroll
  for (int mf = 0; mf < 2; ++mf)
#pragma unroll
    for (int nf = 0; nf < 8; ++nf)
      acc1[mf][nf] = f32x4{0.f, 0.f, 0.f, 0.f};

  // ===== GEMM1: fg_in = cat(hx,x) @ w_f^T =====
  stage_a(sA, x, hx, blockRow, 0, tid);
  stage_b(sB, wf, 0, wave, lane);
  __syncthreads();
#pragma unroll 1
  for (int kt = 0; kt < 24; ++kt) {
    const int cur = kt & 1;
    if (kt < 23) {
      stage_a(sA + (cur ^ 1) * 2048,  x, hx, blockRow, (kt + 1) * 32, tid);
      stage_b(sB + (cur ^ 1) * 16384, wf, (kt + 1) * 32, wave, lane);
    }
    bf16x8 a[2];
    load_a_sa(sA + cur * 2048, a, rl, kg, wm);
    mfma_core(a, sB + cur * 16384, acc1, rl, kg, wn4);
    __syncthreads();
  }

  // prologue for GEMM2 B (async; drains at next barrier)
  stage_b(sB, wn, 0, wave, lane);

  // ===== epilogue1: fg = (fg_in + b_f + 1)/2 (kept in regs); fg_hx -> LDS bf16 =====
#pragma unroll
  for (int nf = 0; nf < 8; ++nf) {
    const int col = wn4 * 128 + nf * 16 + rl;
    const float bfv = bf_[col];
#pragma unroll
    for (int mf = 0; mf < 2; ++mf)
#pragma unroll
      for (int r = 0; r < 4; ++r) {
        const int row = wm * 32 + mf * 16 + kg * 4 + r;
        float fg = (acc1[mf][nf][r] + bfv + 1.0f) * 0.5f;
        acc1[mf][nf][r] = fg;                                   // fg lives in regs
        float hxv = hx[(size_t)(blockRow + row) * 512 + col];
        sFX[(row * 512 + col) ^ ((row & 7) << 3)] = f2bf(fg * hxv);
      }
  }
  __syncthreads();

  // ===== GEMM2: ng = cat(fg_hx, x) @ w_n^T =====
#pragma unroll
  for (int mf = 0; mf < 2; ++mf)
#pragma unroll
    for (int nf = 0; nf < 8; ++nf)
      acc2[mf][nf] = f32x4{0.f, 0.f, 0.f, 0.f};

#pragma unroll 1
  for (int kt = 0; kt < 24; ++kt) {
    const int cur = kt & 1;
    const int k0  = kt * 32;
    if (kt < 23) {
      const int k1 = (kt + 1) * 32;
      if (k1 >= 512) stage_a(sA + (cur ^ 1) * 2048, x, hx, blockRow, k1, tid);
      stage_b(sB + (cur ^ 1) * 16384, wn, k1, wave, lane);
    }
    bf16x8 a[2];
    if (k0 < 512) load_a_fx(sFX, a, k0, rl, kg, wm);
    else          load_a_sa(sA + cur * 2048, a, rl, kg, wm);
    mfma_core(a, sB + cur * 16384, acc2, rl, kg, wn4);
    __syncthreads();
  }

  // ===== epilogue2: hy = ng - fg*ng + fg_hx =====
#pragma unroll
  for (int nf = 0; nf < 8; ++nf) {
    const int col = wn4 * 128 + nf * 16 + rl;
    const float bnv = bn_[col];
#pragma unroll
    for (int mf = 0; mf < 2; ++mf)
#pragma unroll
      for (int r = 0; r < 4; ++r) {
        const int row = wm * 32 + mf * 16 + kg * 4 + r;
        float ng  = acc2[mf][nf][r] + bnv;
        float fg  = acc1[mf][nf][r];
        float fgx = bf2f(sFX[(row * 512 + col) ^ ((row & 7) << 3)]);
        out[(size_t)(blockRow + row) * 512 + col] = ng - fg * ng + fgx;
      }
  }
}

extern "C" void kernel_launch(void* const* d_in, const int* in_sizes, int n_in,
                              void* d_out, int out_size, void* d_ws, size_t ws_size,
                              hipStream_t stream) {
  const float* x   = (const float*)d_in[0];
  const float* hx  = (const float*)d_in[1];
  const float* w_f = (const float*)d_in[2];
  const float* b_f = (const float*)d_in[3];
  const float* w_n = (const float*)d_in[4];
  const float* b_n = (const float*)d_in[5];
  float* out = (float*)d_out;

  uint16_t* wbf = (uint16_t*)d_ws;   // [wf_bf16 | wn_bf16], 1.5 MB total

  convw_kernel<<<768, 256, 0, stream>>>(w_f, w_n, wbf);

  const size_t lds = 8192 + 65536 + 65536;   // 136 KB
  fsumgu_kernel<<<1024, 512, lds, stream>>>(x, hx, b_f, b_n,
                                            wbf, wbf + 393216, out);
}